// Round 1
// baseline (4550.427 us; speedup 1.0000x reference)
//
#include <hip/hip_runtime.h>

#define N_USERS 40000
#define N_ITEMS 60000
#define N_TOTAL 100000
#define NEDGES  600000
#define IN_DIM  128
#define HID     256   // HID == OUT == 256; all activation matrices are [*,256]

// ---------------------------------------------------------------------------
// Tiled fp32 GEMM: C[M,256] = A[M,K] @ B[K,256] (+ bias[col] if bias != null)
// 64x64 output tile per 256-thread block, 4x4 micro-tile per thread, BK=16.
// ---------------------------------------------------------------------------
__global__ __launch_bounds__(256) void gemm_bias(const float* __restrict__ A,
                                                 const float* __restrict__ B,
                                                 const float* __restrict__ bias,
                                                 float* __restrict__ C,
                                                 int M, int K) {
    const int BM = 64, BN = 64, BK = 16;
    __shared__ float As[BK][BM + 1];   // [k][m], +1 pad vs bank conflicts
    __shared__ float Bs[BK][BN];       // [k][n]

    const int m0 = blockIdx.x * BM;
    const int n0 = blockIdx.y * BN;
    const int t  = threadIdx.x;
    const int tx = t & 15;       // 0..15 -> 4 cols each
    const int ty = t >> 4;       // 0..15 -> 4 rows each

    float acc[4][4] = {};

    for (int k0 = 0; k0 < K; k0 += BK) {
        // Load A tile: 64 rows x 16 k (float4 per thread)
        {
            const int m  = t >> 2;          // 0..63
            const int k4 = (t & 3) * 4;     // 0,4,8,12
            const int row = m0 + m;
            float4 a = make_float4(0.f, 0.f, 0.f, 0.f);
            if (row < M)
                a = *reinterpret_cast<const float4*>(A + (size_t)row * K + k0 + k4);
            As[k4 + 0][m] = a.x; As[k4 + 1][m] = a.y;
            As[k4 + 2][m] = a.z; As[k4 + 3][m] = a.w;
        }
        // Load B tile: 16 k x 64 n (float4 per thread, coalesced)
        {
            const int k  = t >> 4;          // 0..15
            const int n4 = (t & 15) * 4;    // 0..60
            float4 b = *reinterpret_cast<const float4*>(B + (size_t)(k0 + k) * HID + n0 + n4);
            Bs[k][n4 + 0] = b.x; Bs[k][n4 + 1] = b.y;
            Bs[k][n4 + 2] = b.z; Bs[k][n4 + 3] = b.w;
        }
        __syncthreads();

        #pragma unroll
        for (int k = 0; k < BK; ++k) {
            float a[4], b[4];
            #pragma unroll
            for (int i = 0; i < 4; ++i) a[i] = As[k][ty * 4 + i];
            #pragma unroll
            for (int j = 0; j < 4; ++j) b[j] = Bs[k][tx * 4 + j];
            #pragma unroll
            for (int i = 0; i < 4; ++i)
                #pragma unroll
                for (int j = 0; j < 4; ++j)
                    acc[i][j] = fmaf(a[i], b[j], acc[i][j]);
        }
        __syncthreads();
    }

    #pragma unroll
    for (int i = 0; i < 4; ++i) {
        const int row = m0 + ty * 4 + i;
        if (row >= M) continue;
        #pragma unroll
        for (int j = 0; j < 4; ++j) {
            const int col = n0 + tx * 4 + j;
            float v = acc[i][j];
            if (bias) v += bias[col];
            C[(size_t)row * HID + col] = v;
        }
    }
}

// ---------------------------------------------------------------------------
// SpMM scatter: Y[rows[e], :] += vals[e] * X[cols[e], :]
// 4 edges per 256-thread block; 64 lanes per edge; float4 gather + 4 atomics.
// ---------------------------------------------------------------------------
__global__ __launch_bounds__(256) void spmm_atomic(const int* __restrict__ rows,
                                                   const int* __restrict__ cols,
                                                   const float* __restrict__ vals,
                                                   const float* __restrict__ X,
                                                   float* __restrict__ Y,
                                                   int n_edges) {
    const int e    = blockIdx.x * 4 + (threadIdx.x >> 6);
    const int lane = threadIdx.x & 63;
    if (e >= n_edges) return;
    const int   r = rows[e];
    const int   c = cols[e];
    const float v = vals[e];
    const float4 xv = *reinterpret_cast<const float4*>(X + (size_t)c * HID + lane * 4);
    float* yp = Y + (size_t)r * HID + lane * 4;
    atomicAdd(yp + 0, v * xv.x);
    atomicAdd(yp + 1, v * xv.y);
    atomicAdd(yp + 2, v * xv.z);
    atomicAdd(yp + 3, v * xv.w);
}

// ---------------------------------------------------------------------------
// In-place ReLU (vectorized)
// ---------------------------------------------------------------------------
__global__ __launch_bounds__(256) void relu_inplace(float* __restrict__ h, long n4) {
    long i = (long)blockIdx.x * blockDim.x + threadIdx.x;
    long stride = (long)gridDim.x * blockDim.x;
    for (; i < n4; i += stride) {
        float4 v = reinterpret_cast<float4*>(h)[i];
        v.x = fmaxf(v.x, 0.f); v.y = fmaxf(v.y, 0.f);
        v.z = fmaxf(v.z, 0.f); v.w = fmaxf(v.w, 0.f);
        reinterpret_cast<float4*>(h)[i] = v;
    }
}

extern "C" void kernel_launch(void* const* d_in, const int* in_sizes, int n_in,
                              void* d_out, int out_size, void* d_ws, size_t ws_size,
                              hipStream_t stream) {
    const float* user_feat = (const float*)d_in[0];
    const float* item_feat = (const float*)d_in[1];
    const int*   edge_rows = (const int*)d_in[2];
    const int*   edge_cols = (const int*)d_in[3];
    const float* edge_vals = (const float*)d_in[4];
    const float* W0    = (const float*)d_in[5];
    const float* b0    = (const float*)d_in[6];
    const float* Wres0 = (const float*)d_in[7];
    const float* W1    = (const float*)d_in[8];
    const float* b1    = (const float*)d_in[9];
    float* out = (float*)d_out;

    float* x = (float*)d_ws;                          // [N_TOTAL, 256]
    float* h = x + (size_t)N_TOTAL * HID;             // [N_TOTAL, 256]

    const dim3 blk(256);
    const dim3 gu((N_USERS + 63) / 64, HID / 64);
    const dim3 gi((N_ITEMS + 63) / 64, HID / 64);
    const dim3 gn((N_TOTAL + 63) / 64, HID / 64);

    // h = res = concat_feat @ Wres0   (acts as SpMM accumulator init)
    gemm_bias<<<gu, blk, 0, stream>>>(user_feat, Wres0, nullptr, h, N_USERS, IN_DIM);
    gemm_bias<<<gi, blk, 0, stream>>>(item_feat, Wres0, nullptr,
                                      h + (size_t)N_USERS * HID, N_ITEMS, IN_DIM);
    // x = concat_feat @ W0 + b0
    gemm_bias<<<gu, blk, 0, stream>>>(user_feat, W0, b0, x, N_USERS, IN_DIM);
    gemm_bias<<<gi, blk, 0, stream>>>(item_feat, W0, b0,
                                      x + (size_t)N_USERS * HID, N_ITEMS, IN_DIM);
    // h += A @ x (scatter)
    spmm_atomic<<<(NEDGES + 3) / 4, blk, 0, stream>>>(edge_rows, edge_cols, edge_vals,
                                                      x, h, NEDGES);
    // h = relu(h)
    relu_inplace<<<2048, blk, 0, stream>>>(h, (long)N_TOTAL * HID / 4);
    // x2 = h @ W1 + b1   (reuse x buffer)
    gemm_bias<<<gn, blk, 0, stream>>>(h, W1, b1, x, N_TOTAL, HID);
    // out = A @ x2 (scatter)
    hipMemsetAsync(d_out, 0, (size_t)out_size * sizeof(float), stream);
    spmm_atomic<<<(NEDGES + 3) / 4, blk, 0, stream>>>(edge_rows, edge_cols, edge_vals,
                                                      x, out, NEDGES);
}

// Round 2
// 833.097 us; speedup vs baseline: 5.4621x; 5.4621x over previous
//
#include <hip/hip_runtime.h>

#define N_USERS 40000
#define N_ITEMS 60000
#define N_TOTAL 100000
#define NEDGES  600000
#define IN_DIM  128
#define HID     256   // HID == OUT == 256

// ---------------------------------------------------------------------------
// Tiled fp32 GEMM: C[M,256] = A[M,K] @ B[K,256] (+ bias[col] if bias != null)
// ---------------------------------------------------------------------------
__global__ __launch_bounds__(256) void gemm_bias(const float* __restrict__ A,
                                                 const float* __restrict__ B,
                                                 const float* __restrict__ bias,
                                                 float* __restrict__ C,
                                                 int M, int K) {
    const int BM = 64, BN = 64, BK = 16;
    __shared__ float As[BK][BM + 1];
    __shared__ float Bs[BK][BN];

    const int m0 = blockIdx.x * BM;
    const int n0 = blockIdx.y * BN;
    const int t  = threadIdx.x;
    const int tx = t & 15;
    const int ty = t >> 4;

    float acc[4][4] = {};

    for (int k0 = 0; k0 < K; k0 += BK) {
        {
            const int m  = t >> 2;
            const int k4 = (t & 3) * 4;
            const int row = m0 + m;
            float4 a = make_float4(0.f, 0.f, 0.f, 0.f);
            if (row < M)
                a = *reinterpret_cast<const float4*>(A + (size_t)row * K + k0 + k4);
            As[k4 + 0][m] = a.x; As[k4 + 1][m] = a.y;
            As[k4 + 2][m] = a.z; As[k4 + 3][m] = a.w;
        }
        {
            const int k  = t >> 4;
            const int n4 = (t & 15) * 4;
            float4 b = *reinterpret_cast<const float4*>(B + (size_t)(k0 + k) * HID + n0 + n4);
            Bs[k][n4 + 0] = b.x; Bs[k][n4 + 1] = b.y;
            Bs[k][n4 + 2] = b.z; Bs[k][n4 + 3] = b.w;
        }
        __syncthreads();

        #pragma unroll
        for (int k = 0; k < BK; ++k) {
            float a[4], b[4];
            #pragma unroll
            for (int i = 0; i < 4; ++i) a[i] = As[k][ty * 4 + i];
            #pragma unroll
            for (int j = 0; j < 4; ++j) b[j] = Bs[k][tx * 4 + j];
            #pragma unroll
            for (int i = 0; i < 4; ++i)
                #pragma unroll
                for (int j = 0; j < 4; ++j)
                    acc[i][j] = fmaf(a[i], b[j], acc[i][j]);
        }
        __syncthreads();
    }

    #pragma unroll
    for (int i = 0; i < 4; ++i) {
        const int row = m0 + ty * 4 + i;
        if (row >= M) continue;
        #pragma unroll
        for (int j = 0; j < 4; ++j) {
            const int col = n0 + tx * 4 + j;
            float v = acc[i][j];
            if (bias) v += bias[col];
            C[(size_t)row * HID + col] = v;
        }
    }
}

// ---------------------------------------------------------------------------
// CSR build: histogram -> exclusive scan (3 kernels) -> fill slots
// ---------------------------------------------------------------------------
__global__ __launch_bounds__(256) void edge_histogram(const int* __restrict__ rows,
                                                      int* __restrict__ cnt) {
    int e = blockIdx.x * 256 + threadIdx.x;
    if (e < NEDGES) atomicAdd(&cnt[rows[e]], 1);
}

#define SCAN_B 1024
__global__ __launch_bounds__(SCAN_B) void scan_blocks(const int* __restrict__ cnt,
                                                      int* __restrict__ row_ptr,
                                                      int* __restrict__ bsums) {
    __shared__ int s[SCAN_B];
    const int gid = blockIdx.x * SCAN_B + threadIdx.x;
    const int v = (gid < N_TOTAL) ? cnt[gid] : 0;
    s[threadIdx.x] = v;
    __syncthreads();
    for (int off = 1; off < SCAN_B; off <<= 1) {
        int t = (threadIdx.x >= off) ? s[threadIdx.x - off] : 0;
        __syncthreads();
        s[threadIdx.x] += t;
        __syncthreads();
    }
    if (gid < N_TOTAL) row_ptr[gid] = s[threadIdx.x] - v;   // exclusive
    if (threadIdx.x == SCAN_B - 1) bsums[blockIdx.x] = s[threadIdx.x];
}

__global__ __launch_bounds__(128) void scan_sums(int* __restrict__ bsums, int nb) {
    __shared__ int s[128];
    const int v = (threadIdx.x < nb) ? bsums[threadIdx.x] : 0;
    s[threadIdx.x] = v;
    __syncthreads();
    for (int off = 1; off < 128; off <<= 1) {
        int t = (threadIdx.x >= off) ? s[threadIdx.x - off] : 0;
        __syncthreads();
        s[threadIdx.x] += t;
        __syncthreads();
    }
    if (threadIdx.x < nb) bsums[threadIdx.x] = s[threadIdx.x] - v;  // exclusive
}

__global__ __launch_bounds__(SCAN_B) void scan_apply(int* __restrict__ row_ptr,
                                                     const int* __restrict__ bsums,
                                                     int* __restrict__ next) {
    const int gid = blockIdx.x * SCAN_B + threadIdx.x;
    if (gid < N_TOTAL) {
        const int p = row_ptr[gid] + bsums[blockIdx.x];
        row_ptr[gid] = p;
        next[gid] = p;
    }
    if (gid == 0) row_ptr[N_TOTAL] = NEDGES;
}

__global__ __launch_bounds__(256) void csr_fill(const int* __restrict__ rows,
                                                const int* __restrict__ cols,
                                                const float* __restrict__ vals,
                                                int* __restrict__ next,
                                                int* __restrict__ ccol,
                                                float* __restrict__ cval) {
    int e = blockIdx.x * 256 + threadIdx.x;
    if (e >= NEDGES) return;
    const int slot = atomicAdd(&next[rows[e]], 1);
    ccol[slot] = cols[e];
    cval[slot] = vals[e];
}

// ---------------------------------------------------------------------------
// Gather SpMM: one 64-lane wave per row. Y[r,:] = sum_e val*X[col,:]
// FUSE: Y = relu(acc + RES[r,:]) for layer 0.
// ---------------------------------------------------------------------------
template <bool FUSE_RES_RELU>
__global__ __launch_bounds__(256) void spmm_csr(const int* __restrict__ row_ptr,
                                                const int* __restrict__ ccol,
                                                const float* __restrict__ cval,
                                                const float* __restrict__ X,
                                                const float* __restrict__ RES,
                                                float* __restrict__ Y) {
    const int wid  = (blockIdx.x * 256 + threadIdx.x) >> 6;  // row
    const int lane = threadIdx.x & 63;
    if (wid >= N_TOTAL) return;
    const int beg = row_ptr[wid];
    const int end = row_ptr[wid + 1];

    float4 acc = make_float4(0.f, 0.f, 0.f, 0.f);
    for (int e = beg; e < end; ++e) {
        const int   c = ccol[e];
        const float v = cval[e];
        const float4 xv = *reinterpret_cast<const float4*>(X + (size_t)c * HID + lane * 4);
        acc.x = fmaf(v, xv.x, acc.x);
        acc.y = fmaf(v, xv.y, acc.y);
        acc.z = fmaf(v, xv.z, acc.z);
        acc.w = fmaf(v, xv.w, acc.w);
    }
    float* yp = Y + (size_t)wid * HID + lane * 4;
    if (FUSE_RES_RELU) {
        const float4 r = *reinterpret_cast<const float4*>(RES + (size_t)wid * HID + lane * 4);
        acc.x = fmaxf(acc.x + r.x, 0.f);
        acc.y = fmaxf(acc.y + r.y, 0.f);
        acc.z = fmaxf(acc.z + r.z, 0.f);
        acc.w = fmaxf(acc.w + r.w, 0.f);
    }
    *reinterpret_cast<float4*>(yp) = acc;
}

extern "C" void kernel_launch(void* const* d_in, const int* in_sizes, int n_in,
                              void* d_out, int out_size, void* d_ws, size_t ws_size,
                              hipStream_t stream) {
    const float* user_feat = (const float*)d_in[0];
    const float* item_feat = (const float*)d_in[1];
    const int*   edge_rows = (const int*)d_in[2];
    const int*   edge_cols = (const int*)d_in[3];
    const float* edge_vals = (const float*)d_in[4];
    const float* W0    = (const float*)d_in[5];
    const float* b0    = (const float*)d_in[6];
    const float* Wres0 = (const float*)d_in[7];
    const float* W1    = (const float*)d_in[8];
    const float* b1    = (const float*)d_in[9];
    float* out = (float*)d_out;

    // Workspace layout
    char* ws = (char*)d_ws;
    float* x       = (float*)ws;                       ws += (size_t)N_TOTAL * HID * 4;  // 102.4 MB
    float* h       = (float*)ws;                       ws += (size_t)N_TOTAL * HID * 4;  // 102.4 MB
    int*   row_ptr = (int*)ws;                         ws += (N_TOTAL + 1) * 4;
    int*   cnt     = (int*)ws;                         ws += N_TOTAL * 4;
    int*   nxt     = (int*)ws;                         ws += N_TOTAL * 4;
    int*   bsums   = (int*)ws;                         ws += 128 * 4;
    int*   ccol    = (int*)ws;                         ws += NEDGES * 4;
    float* cval    = (float*)ws;                       ws += NEDGES * 4;

    const dim3 blk(256);
    const int nscan = (N_TOTAL + SCAN_B - 1) / SCAN_B;   // 98

    // ---- CSR build ----
    hipMemsetAsync(cnt, 0, N_TOTAL * 4, stream);
    edge_histogram<<<(NEDGES + 255) / 256, blk, 0, stream>>>(edge_rows, cnt);
    scan_blocks<<<nscan, SCAN_B, 0, stream>>>(cnt, row_ptr, bsums);
    scan_sums<<<1, 128, 0, stream>>>(bsums, nscan);
    scan_apply<<<nscan, SCAN_B, 0, stream>>>(row_ptr, bsums, nxt);
    csr_fill<<<(NEDGES + 255) / 256, blk, 0, stream>>>(edge_rows, edge_cols, edge_vals,
                                                       nxt, ccol, cval);

    // ---- Layer 0 dense parts ----
    const dim3 gu((N_USERS + 63) / 64, HID / 64);
    const dim3 gi((N_ITEMS + 63) / 64, HID / 64);
    const dim3 gn((N_TOTAL + 63) / 64, HID / 64);

    // h = res = concat_feat @ Wres0
    gemm_bias<<<gu, blk, 0, stream>>>(user_feat, Wres0, nullptr, h, N_USERS, IN_DIM);
    gemm_bias<<<gi, blk, 0, stream>>>(item_feat, Wres0, nullptr,
                                      h + (size_t)N_USERS * HID, N_ITEMS, IN_DIM);
    // x = concat_feat @ W0 + b0
    gemm_bias<<<gu, blk, 0, stream>>>(user_feat, W0, b0, x, N_USERS, IN_DIM);
    gemm_bias<<<gi, blk, 0, stream>>>(item_feat, W0, b0,
                                      x + (size_t)N_USERS * HID, N_ITEMS, IN_DIM);

    // h = relu(spmm(x) + h)   [gather, fused residual+relu]
    const int spmm_blocks = (N_TOTAL * 64 + 255) / 256;  // 1 wave per row
    spmm_csr<true><<<spmm_blocks, blk, 0, stream>>>(row_ptr, ccol, cval, x, h, h);

    // x2 = h @ W1 + b1
    gemm_bias<<<gn, blk, 0, stream>>>(h, W1, b1, x, N_TOTAL, HID);

    // out = spmm(x2)   [every row written -> no memset needed]
    spmm_csr<false><<<spmm_blocks, blk, 0, stream>>>(row_ptr, ccol, cval, x, nullptr, out);
}

// Round 3
// 460.276 us; speedup vs baseline: 9.8863x; 1.8100x over previous
//
#include <hip/hip_runtime.h>

#define N_USERS 40000
#define N_ITEMS 60000
#define N_TOTAL 100000
#define M_PAD   100032   // row count padded to multiple of 64
#define NEDGES  600000
#define IN_DIM  128
#define HID     256

typedef short  bf16x8 __attribute__((ext_vector_type(8)));
typedef float  f32x4  __attribute__((ext_vector_type(4)));
typedef unsigned short ushort4v __attribute__((ext_vector_type(4)));
typedef unsigned short ushort8v __attribute__((ext_vector_type(8)));

__device__ __forceinline__ unsigned short f2bf(float f) {   // RNE fp32->bf16
    unsigned u = __builtin_bit_cast(unsigned, f);
    unsigned r = (u + 0x7FFFu + ((u >> 16) & 1u)) >> 16;
    return (unsigned short)r;
}
__device__ __forceinline__ float bf2f(unsigned short b) {
    unsigned u = ((unsigned)b) << 16;
    return __builtin_bit_cast(float, u);
}

// ---------------------------------------------------------------------------
// Prep: feats fp32 -> bf16 (concat user+item), 8 elems/thread
// ---------------------------------------------------------------------------
__global__ __launch_bounds__(256) void prep_feats(const float* __restrict__ uf,
                                                  const float* __restrict__ itf,
                                                  unsigned short* __restrict__ outp) {
    const long i8 = (long)(blockIdx.x * 256 + threadIdx.x) * 8;
    if (i8 >= (long)N_TOTAL * IN_DIM) return;
    const long uend = (long)N_USERS * IN_DIM;
    const float4* src = (i8 < uend) ? (const float4*)(uf + i8)
                                    : (const float4*)(itf + (i8 - uend));
    float4 a = src[0], b = src[1];
    ushort8v o;
    o[0] = f2bf(a.x); o[1] = f2bf(a.y); o[2] = f2bf(a.z); o[3] = f2bf(a.w);
    o[4] = f2bf(b.x); o[5] = f2bf(b.y); o[6] = f2bf(b.z); o[7] = f2bf(b.w);
    *(ushort8v*)(outp + i8) = o;
}

// ---------------------------------------------------------------------------
// Prep: weights -> transposed bf16. Wcat_t[512][128] = [W0 | Wres0]^T,
// W1_t[256][256] = W1^T. Tiny (512 KB fp32 read), uncoalesced ok.
// ---------------------------------------------------------------------------
__global__ __launch_bounds__(256) void prep_weights(const float* __restrict__ W0,
                                                    const float* __restrict__ Wres0,
                                                    const float* __restrict__ W1,
                                                    unsigned short* __restrict__ Wcat_t,
                                                    unsigned short* __restrict__ W1_t) {
    const int id = blockIdx.x * 256 + threadIdx.x;
    if (id < 512 * IN_DIM) {
        const int n = id >> 7, k = id & 127;
        const float v = (n < HID) ? W0[(size_t)k * HID + n]
                                  : Wres0[(size_t)k * HID + (n - HID)];
        Wcat_t[id] = f2bf(v);
    } else {
        const int id2 = id - 512 * IN_DIM;          // 0..65535
        const int n = id2 >> 8, k = id2 & 255;
        W1_t[id2] = f2bf(W1[(size_t)k * HID + n]);
    }
}

// ---------------------------------------------------------------------------
// MFMA GEMM: C[M,N] = A[M,K]_bf16 @ Bt[N,K]_bf16^T, fp32 acc, bf16 out.
// 64x64 tile, 4 waves (wave w -> rows 16w..16w+15, 4 n-tiles of 16).
// EPI=0: out0 = acc + bias (layer 1).  EPI=1: col<256 -> out0=acc+bias (x),
// col>=256 -> out1=acc (res), for the fused W0|Wres0 layer-0 pass.
// ---------------------------------------------------------------------------
template <int K, int EPI>
__global__ __launch_bounds__(256) void mfma_gemm(const unsigned short* __restrict__ A,
                                                 const unsigned short* __restrict__ Bt,
                                                 const float* __restrict__ bias,
                                                 unsigned short* __restrict__ out0,
                                                 unsigned short* __restrict__ out1) {
    __shared__ unsigned short As[64 * 32];
    __shared__ unsigned short Bs[64 * 32];
    const int t  = threadIdx.x;
    const int m0 = blockIdx.x * 64;
    const int n0 = blockIdx.y * 64;
    const int w  = t >> 6, l = t & 63;
    const int fr = l & 15, fb = l >> 4;

    f32x4 acc[4] = {};
    const unsigned short* Ap = A  + (size_t)(m0 + (t >> 2)) * K + (t & 3) * 8;
    const unsigned short* Bp = Bt + (size_t)(n0 + (t >> 2)) * K + (t & 3) * 8;

    for (int kk = 0; kk < K; kk += 32) {
        const ushort8v av = *(const ushort8v*)(Ap + kk);
        const ushort8v bv = *(const ushort8v*)(Bp + kk);
        __syncthreads();
        *(ushort8v*)(As + t * 8) = av;   // [row][k] row-major: (t>>2)*32+(t&3)*8 == t*8
        *(ushort8v*)(Bs + t * 8) = bv;
        __syncthreads();
        const bf16x8 af = *(const bf16x8*)(As + (16 * w + fr) * 32 + fb * 8);
        #pragma unroll
        for (int nt = 0; nt < 4; ++nt) {
            const bf16x8 bfr = *(const bf16x8*)(Bs + (nt * 16 + fr) * 32 + fb * 8);
            acc[nt] = __builtin_amdgcn_mfma_f32_16x16x32_bf16(af, bfr, acc[nt], 0, 0, 0);
        }
    }

    #pragma unroll
    for (int nt = 0; nt < 4; ++nt) {
        const int col = n0 + nt * 16 + fr;
        #pragma unroll
        for (int r = 0; r < 4; ++r) {
            const int row = m0 + 16 * w + fb * 4 + r;   // C/D: col=lane&15, row=(lane>>4)*4+reg
            if (row >= N_TOTAL) continue;
            const float v = acc[nt][r];
            if (EPI == 0) {
                out0[(size_t)row * HID + col] = f2bf(v + bias[col]);
            } else {
                if (col < HID) out0[(size_t)row * HID + col] = f2bf(v + bias[col]);
                else           out1[(size_t)row * HID + (col - HID)] = f2bf(v);
            }
        }
    }
}

// ---------------------------------------------------------------------------
// CSR build: histogram -> exclusive scan -> fill
// ---------------------------------------------------------------------------
__global__ __launch_bounds__(256) void edge_histogram(const int* __restrict__ rows,
                                                      int* __restrict__ cnt) {
    int e = blockIdx.x * 256 + threadIdx.x;
    if (e < NEDGES) atomicAdd(&cnt[rows[e]], 1);
}

#define SCAN_B 1024
__global__ __launch_bounds__(SCAN_B) void scan_blocks(const int* __restrict__ cnt,
                                                      int* __restrict__ row_ptr,
                                                      int* __restrict__ bsums) {
    __shared__ int s[SCAN_B];
    const int gid = blockIdx.x * SCAN_B + threadIdx.x;
    const int v = (gid < N_TOTAL) ? cnt[gid] : 0;
    s[threadIdx.x] = v;
    __syncthreads();
    for (int off = 1; off < SCAN_B; off <<= 1) {
        int tv = (threadIdx.x >= off) ? s[threadIdx.x - off] : 0;
        __syncthreads();
        s[threadIdx.x] += tv;
        __syncthreads();
    }
    if (gid < N_TOTAL) row_ptr[gid] = s[threadIdx.x] - v;
    if (threadIdx.x == SCAN_B - 1) bsums[blockIdx.x] = s[threadIdx.x];
}

__global__ __launch_bounds__(128) void scan_sums(int* __restrict__ bsums, int nb) {
    __shared__ int s[128];
    const int v = (threadIdx.x < nb) ? bsums[threadIdx.x] : 0;
    s[threadIdx.x] = v;
    __syncthreads();
    for (int off = 1; off < 128; off <<= 1) {
        int tv = (threadIdx.x >= off) ? s[threadIdx.x - off] : 0;
        __syncthreads();
        s[threadIdx.x] += tv;
        __syncthreads();
    }
    if (threadIdx.x < nb) bsums[threadIdx.x] = s[threadIdx.x] - v;
}

__global__ __launch_bounds__(SCAN_B) void scan_apply(int* __restrict__ row_ptr,
                                                     const int* __restrict__ bsums,
                                                     int* __restrict__ next) {
    const int gid = blockIdx.x * SCAN_B + threadIdx.x;
    if (gid < N_TOTAL) {
        const int p = row_ptr[gid] + bsums[blockIdx.x];
        row_ptr[gid] = p;
        next[gid] = p;
    }
    if (gid == 0) row_ptr[N_TOTAL] = NEDGES;
}

__global__ __launch_bounds__(256) void csr_fill(const int* __restrict__ rows,
                                                const int* __restrict__ cols,
                                                const float* __restrict__ vals,
                                                int* __restrict__ next,
                                                int* __restrict__ ccol,
                                                float* __restrict__ cval) {
    int e = blockIdx.x * 256 + threadIdx.x;
    if (e >= NEDGES) return;
    const int slot = atomicAdd(&next[rows[e]], 1);
    ccol[slot] = cols[e];
    cval[slot] = vals[e];
}

// ---------------------------------------------------------------------------
// Gather SpMM, bf16 X. One 64-lane wave per row, 4 cols/lane, 2-edge unroll.
// FUSE: in-place h = relu(acc + h) written bf16. Else: write fp32 out.
// ---------------------------------------------------------------------------
template <bool FUSE>
__global__ __launch_bounds__(256) void spmm_bf16(const int* __restrict__ row_ptr,
                                                 const int* __restrict__ ccol,
                                                 const float* __restrict__ cval,
                                                 const unsigned short* __restrict__ X,
                                                 unsigned short* __restrict__ Ybf,
                                                 float* __restrict__ Yf) {
    const int wid  = (blockIdx.x * 256 + threadIdx.x) >> 6;
    const int lane = threadIdx.x & 63;
    if (wid >= N_TOTAL) return;
    const int beg = row_ptr[wid], end = row_ptr[wid + 1];

    float a0 = 0.f, a1 = 0.f, a2 = 0.f, a3 = 0.f;
    int e = beg;
    for (; e + 1 < end; e += 2) {
        const int   c0 = ccol[e],     c1 = ccol[e + 1];
        const float v0 = cval[e],     v1 = cval[e + 1];
        const ushort4v x0 = *(const ushort4v*)(X + (size_t)c0 * HID + lane * 4);
        const ushort4v x1 = *(const ushort4v*)(X + (size_t)c1 * HID + lane * 4);
        a0 = fmaf(v0, bf2f(x0[0]), a0); a1 = fmaf(v0, bf2f(x0[1]), a1);
        a2 = fmaf(v0, bf2f(x0[2]), a2); a3 = fmaf(v0, bf2f(x0[3]), a3);
        a0 = fmaf(v1, bf2f(x1[0]), a0); a1 = fmaf(v1, bf2f(x1[1]), a1);
        a2 = fmaf(v1, bf2f(x1[2]), a2); a3 = fmaf(v1, bf2f(x1[3]), a3);
    }
    if (e < end) {
        const int   c0 = ccol[e];
        const float v0 = cval[e];
        const ushort4v x0 = *(const ushort4v*)(X + (size_t)c0 * HID + lane * 4);
        a0 = fmaf(v0, bf2f(x0[0]), a0); a1 = fmaf(v0, bf2f(x0[1]), a1);
        a2 = fmaf(v0, bf2f(x0[2]), a2); a3 = fmaf(v0, bf2f(x0[3]), a3);
    }

    if (FUSE) {
        unsigned short* yp = Ybf + (size_t)wid * HID + lane * 4;
        const ushort4v rv = *(const ushort4v*)yp;
        a0 = fmaxf(a0 + bf2f(rv[0]), 0.f);
        a1 = fmaxf(a1 + bf2f(rv[1]), 0.f);
        a2 = fmaxf(a2 + bf2f(rv[2]), 0.f);
        a3 = fmaxf(a3 + bf2f(rv[3]), 0.f);
        ushort4v o; o[0] = f2bf(a0); o[1] = f2bf(a1); o[2] = f2bf(a2); o[3] = f2bf(a3);
        *(ushort4v*)yp = o;
    } else {
        f32x4 o = {a0, a1, a2, a3};
        *(f32x4*)(Yf + (size_t)wid * HID + lane * 4) = o;
    }
}

extern "C" void kernel_launch(void* const* d_in, const int* in_sizes, int n_in,
                              void* d_out, int out_size, void* d_ws, size_t ws_size,
                              hipStream_t stream) {
    const float* user_feat = (const float*)d_in[0];
    const float* item_feat = (const float*)d_in[1];
    const int*   edge_rows = (const int*)d_in[2];
    const int*   edge_cols = (const int*)d_in[3];
    const float* edge_vals = (const float*)d_in[4];
    const float* W0    = (const float*)d_in[5];
    const float* b0    = (const float*)d_in[6];
    const float* Wres0 = (const float*)d_in[7];
    const float* W1    = (const float*)d_in[8];
    const float* b1    = (const float*)d_in[9];
    float* out = (float*)d_out;

    // Workspace layout (256B-aligned segments)
    char* ws = (char*)d_ws;
    auto take = [&](size_t bytes) { char* p = ws; ws += (bytes + 255) & ~(size_t)255; return p; };
    unsigned short* x      = (unsigned short*)take((size_t)M_PAD * HID * 2);    // 51.2 MB
    unsigned short* h      = (unsigned short*)take((size_t)M_PAD * HID * 2);    // 51.2 MB
    unsigned short* feats  = (unsigned short*)take((size_t)M_PAD * IN_DIM * 2); // 25.6 MB
    unsigned short* Wcat_t = (unsigned short*)take(512 * IN_DIM * 2);
    unsigned short* W1_t   = (unsigned short*)take(HID * HID * 2);
    int*   row_ptr = (int*)take((N_TOTAL + 1) * 4);
    int*   cnt     = (int*)take(N_TOTAL * 4);
    int*   nxt     = (int*)take(N_TOTAL * 4);
    int*   bsums   = (int*)take(128 * 4);
    int*   ccol    = (int*)take(NEDGES * 4);
    float* cval    = (float*)take(NEDGES * 4);

    const dim3 blk(256);
    const int nscan = (N_TOTAL + SCAN_B - 1) / SCAN_B;

    // ---- Prep (bf16 casts) ----
    prep_feats<<<(N_TOTAL * IN_DIM / 8 + 255) / 256, blk, 0, stream>>>(user_feat, item_feat, feats);
    prep_weights<<<(512 * IN_DIM + HID * HID) / 256, blk, 0, stream>>>(W0, Wres0, W1, Wcat_t, W1_t);

    // ---- CSR build ----
    hipMemsetAsync(cnt, 0, N_TOTAL * 4, stream);
    edge_histogram<<<(NEDGES + 255) / 256, blk, 0, stream>>>(edge_rows, cnt);
    scan_blocks<<<nscan, SCAN_B, 0, stream>>>(cnt, row_ptr, bsums);
    scan_sums<<<1, 128, 0, stream>>>(bsums, nscan);
    scan_apply<<<nscan, SCAN_B, 0, stream>>>(row_ptr, bsums, nxt);
    csr_fill<<<(NEDGES + 255) / 256, blk, 0, stream>>>(edge_rows, edge_cols, edge_vals,
                                                       nxt, ccol, cval);

    // ---- Layer 0: fused x = A@W0+b0 (cols 0-255), h = A@Wres0 (cols 256-511) ----
    mfma_gemm<IN_DIM, 1><<<dim3(M_PAD / 64, 8), blk, 0, stream>>>(feats, Wcat_t, b0, x, h);

    // ---- h = relu(spmm(x) + h), in place, bf16 ----
    const int spmm_blocks = (N_TOTAL * 64 + 255) / 256;
    spmm_bf16<true><<<spmm_blocks, blk, 0, stream>>>(row_ptr, ccol, cval, x, h, nullptr);

    // ---- Layer 1: x2 = h@W1 + b1 (bf16, reuse x) ----
    mfma_gemm<HID, 0><<<dim3(M_PAD / 64, 4), blk, 0, stream>>>(h, W1_t, b1, x, nullptr);

    // ---- out = spmm(x2), fp32 ----
    spmm_bf16<false><<<spmm_blocks, blk, 0, stream>>>(row_ptr, ccol, cval, x, nullptr, out);
}

// Round 4
// 458.484 us; speedup vs baseline: 9.9249x; 1.0039x over previous
//
#include <hip/hip_runtime.h>

#define N_USERS 40000
#define N_ITEMS 60000
#define N_TOTAL 100000
#define M_PAD   100032   // rows padded to multiple of 64
#define NEDGES  600000
#define IN_DIM  128
#define HID     256

typedef short  bf16x8 __attribute__((ext_vector_type(8)));
typedef float  f32x4  __attribute__((ext_vector_type(4)));
typedef unsigned short ushort4v __attribute__((ext_vector_type(4)));
typedef unsigned short ushort8v __attribute__((ext_vector_type(8)));

__device__ __forceinline__ unsigned short f2bf(float f) {   // RNE fp32->bf16
    unsigned u = __builtin_bit_cast(unsigned, f);
    unsigned r = (u + 0x7FFFu + ((u >> 16) & 1u)) >> 16;
    return (unsigned short)r;
}
__device__ __forceinline__ float bf2f(unsigned short b) {
    unsigned u = ((unsigned)b) << 16;
    return __builtin_bit_cast(float, u);
}

__device__ __forceinline__ void gload_lds16(const void* g, void* l) {
    __builtin_amdgcn_global_load_lds(
        (const __attribute__((address_space(1))) unsigned int*)g,
        (__attribute__((address_space(3))) unsigned int*)l, 16, 0, 0);
}

// ---------------------------------------------------------------------------
// Prep: feats fp32 -> bf16 (concat user+item)
// ---------------------------------------------------------------------------
__global__ __launch_bounds__(256) void prep_feats(const float* __restrict__ uf,
                                                  const float* __restrict__ itf,
                                                  unsigned short* __restrict__ outp) {
    const long i8 = (long)(blockIdx.x * 256 + threadIdx.x) * 8;
    if (i8 >= (long)N_TOTAL * IN_DIM) return;
    const long uend = (long)N_USERS * IN_DIM;
    const float4* src = (i8 < uend) ? (const float4*)(uf + i8)
                                    : (const float4*)(itf + (i8 - uend));
    float4 a = src[0], b = src[1];
    ushort8v o;
    o[0] = f2bf(a.x); o[1] = f2bf(a.y); o[2] = f2bf(a.z); o[3] = f2bf(a.w);
    o[4] = f2bf(b.x); o[5] = f2bf(b.y); o[6] = f2bf(b.z); o[7] = f2bf(b.w);
    *(ushort8v*)(outp + i8) = o;
}

// ---------------------------------------------------------------------------
// Prep: weights -> transposed bf16. Wcat_t[512][128] = [W0 | Wres0]^T,
// W1_t[256][256] = W1^T.
// ---------------------------------------------------------------------------
__global__ __launch_bounds__(256) void prep_weights(const float* __restrict__ W0,
                                                    const float* __restrict__ Wres0,
                                                    const float* __restrict__ W1,
                                                    unsigned short* __restrict__ Wcat_t,
                                                    unsigned short* __restrict__ W1_t) {
    const int id = blockIdx.x * 256 + threadIdx.x;
    if (id < 512 * IN_DIM) {
        const int n = id >> 7, k = id & 127;
        const float v = (n < HID) ? W0[(size_t)k * HID + n]
                                  : Wres0[(size_t)k * HID + (n - HID)];
        Wcat_t[id] = f2bf(v);
    } else {
        const int id2 = id - 512 * IN_DIM;
        const int n = id2 >> 8, k = id2 & 255;
        W1_t[id2] = f2bf(W1[(size_t)k * HID + n]);
    }
}

// ---------------------------------------------------------------------------
// Stage one B chunk [256 rows][32 k] (16 KB) into LDS, linear layout.
// ---------------------------------------------------------------------------
template <int K>
__device__ __forceinline__ void stageB(const unsigned short* __restrict__ Bg,
                                       char* bs, int kk, int t) {
    #pragma unroll
    for (int i = 0; i < 4; ++i) {
        const int L = (i * 256 + t) * 16;   // byte in Bs buffer
        const int n = L >> 6;               // Bt row (output col)
        const int q = (L >> 4) & 3;         // 16B chunk within 64B row
        gload_lds16((const char*)(Bg + (size_t)n * K + kk + q * 8), bs + L);
    }
}

// ---------------------------------------------------------------------------
// MFMA GEMM v2: C[M,256] = A[M,K] @ Bt[colgrp*256+n][K]^T, fp32 acc, bf16 out.
// Block: 64 rows x 256 cols, 4 waves in 2x2 (wave tile 32x128).
// A panel staged ONCE (XOR-swizzled via pre-swizzled global source);
// B double-buffered in 32-K chunks (2-phase pipeline).
// EPI=0: out0 = acc + bias.  EPI=1: gy==0 -> out0=acc+bias (x); gy==1 -> out1=acc (res).
// ---------------------------------------------------------------------------
template <int K, int EPI>
__global__ __launch_bounds__(256) void mfma_gemm2(const unsigned short* __restrict__ A,
                                                  const unsigned short* __restrict__ Bt,
                                                  const float* __restrict__ bias,
                                                  unsigned short* __restrict__ out0,
                                                  unsigned short* __restrict__ out1) {
    constexpr int NK    = K / 32;
    constexpr int SHIFT = (K == 256) ? 9 : 8;       // log2(row bytes) of As
    __shared__ unsigned short As[64 * K];
    __shared__ unsigned short Bs[2][256 * 32];

    const int t  = threadIdx.x;
    const int w  = t >> 6, l = t & 63;
    const int fr = l & 15, fb = l >> 4;
    const int wr = w >> 1, wc = w & 1;              // 2x2 wave grid
    const int m0 = blockIdx.x * 64;
    const int gy = blockIdx.y;                      // column group (layer0: 0/1)

    // ---- stage As: contiguous 64xK panel; source pre-swizzled, dest linear ----
    const char* Ag = (const char*)(A + (size_t)m0 * K);
    constexpr int ACALLS = (64 * K * 2) / (16 * 256);
    #pragma unroll
    for (int i = 0; i < ACALLS; ++i) {
        const int L = (i * 256 + t) * 16;                 // storage byte (linear)
        const int U = L ^ (((L >> SHIFT) & 7) << 4);      // unswizzled source byte
        gload_lds16(Ag + U, (char*)As + L);
    }
    const unsigned short* Bg = Bt + (size_t)gy * 256 * K;
    stageB<K>(Bg, (char*)Bs[0], 0, t);
    __syncthreads();

    f32x4 acc[2][8] = {};
    for (int kt = 0; kt < NK; ++kt) {
        if (kt + 1 < NK) stageB<K>(Bg, (char*)Bs[(kt + 1) & 1], (kt + 1) * 32, t);

        const char* as_base = (const char*)As;
        const char* bs_base = (const char*)Bs[kt & 1];
        bf16x8 af[2];
        #pragma unroll
        for (int rb = 0; rb < 2; ++rb) {
            const int row = wr * 32 + rb * 16 + fr;
            const int Sa = ((row * K + kt * 32 + fb * 8) * 2) ^ ((fr & 7) << 4);
            af[rb] = *(const bf16x8*)(as_base + Sa);
        }
        #pragma unroll
        for (int nt = 0; nt < 8; ++nt) {
            const int Sb = ((wc * 128 + nt * 16 + fr) * 32 + fb * 8) * 2;
            const bf16x8 bfr = *(const bf16x8*)(bs_base + Sb);
            acc[0][nt] = __builtin_amdgcn_mfma_f32_16x16x32_bf16(af[0], bfr, acc[0][nt], 0, 0, 0);
            acc[1][nt] = __builtin_amdgcn_mfma_f32_16x16x32_bf16(af[1], bfr, acc[1][nt], 0, 0, 0);
        }
        __syncthreads();   // drains the async B-stage (vmcnt) + guards dbuf swap
    }

    // ---- epilogue ----
    const bool use1 = (EPI == 1) && (gy == 1);
    unsigned short* outp = use1 ? out1 : out0;
    #pragma unroll
    for (int rb = 0; rb < 2; ++rb) {
        #pragma unroll
        for (int nt = 0; nt < 8; ++nt) {
            const int col = wc * 128 + nt * 16 + fr;
            const float bv = use1 ? 0.f : bias[col];
            #pragma unroll
            for (int j = 0; j < 4; ++j) {
                const int row = m0 + wr * 32 + rb * 16 + fb * 4 + j;
                if (row < N_TOTAL)
                    outp[(size_t)row * HID + col] = f2bf(acc[rb][nt][j] + bv);
            }
        }
    }
}

// ---------------------------------------------------------------------------
// CSR build: histogram -> exclusive scan -> fill (col,val packed as int2)
// ---------------------------------------------------------------------------
__global__ __launch_bounds__(256) void edge_histogram(const int* __restrict__ rows,
                                                      int* __restrict__ cnt) {
    int e = blockIdx.x * 256 + threadIdx.x;
    if (e < NEDGES) atomicAdd(&cnt[rows[e]], 1);
}

#define SCAN_B 1024
__global__ __launch_bounds__(SCAN_B) void scan_blocks(const int* __restrict__ cnt,
                                                      int* __restrict__ row_ptr,
                                                      int* __restrict__ bsums) {
    __shared__ int s[SCAN_B];
    const int gid = blockIdx.x * SCAN_B + threadIdx.x;
    const int v = (gid < N_TOTAL) ? cnt[gid] : 0;
    s[threadIdx.x] = v;
    __syncthreads();
    for (int off = 1; off < SCAN_B; off <<= 1) {
        int tv = (threadIdx.x >= off) ? s[threadIdx.x - off] : 0;
        __syncthreads();
        s[threadIdx.x] += tv;
        __syncthreads();
    }
    if (gid < N_TOTAL) row_ptr[gid] = s[threadIdx.x] - v;
    if (threadIdx.x == SCAN_B - 1) bsums[blockIdx.x] = s[threadIdx.x];
}

__global__ __launch_bounds__(128) void scan_sums(int* __restrict__ bsums, int nb) {
    __shared__ int s[128];
    const int v = (threadIdx.x < nb) ? bsums[threadIdx.x] : 0;
    s[threadIdx.x] = v;
    __syncthreads();
    for (int off = 1; off < 128; off <<= 1) {
        int tv = (threadIdx.x >= off) ? s[threadIdx.x - off] : 0;
        __syncthreads();
        s[threadIdx.x] += tv;
        __syncthreads();
    }
    if (threadIdx.x < nb) bsums[threadIdx.x] = s[threadIdx.x] - v;
}

__global__ __launch_bounds__(SCAN_B) void scan_apply(int* __restrict__ row_ptr,
                                                     const int* __restrict__ bsums,
                                                     int* __restrict__ next) {
    const int gid = blockIdx.x * SCAN_B + threadIdx.x;
    if (gid < N_TOTAL) {
        const int p = row_ptr[gid] + bsums[blockIdx.x];
        row_ptr[gid] = p;
        next[gid] = p;
    }
    if (gid == 0) row_ptr[N_TOTAL] = NEDGES;
}

__global__ __launch_bounds__(256) void csr_fill(const int* __restrict__ rows,
                                                const int* __restrict__ cols,
                                                const float* __restrict__ vals,
                                                int* __restrict__ next,
                                                int2* __restrict__ cvp) {
    int e = blockIdx.x * 256 + threadIdx.x;
    if (e >= NEDGES) return;
    const int slot = atomicAdd(&next[rows[e]], 1);
    int2 p;
    p.x = cols[e];
    p.y = __builtin_bit_cast(int, vals[e]);
    cvp[slot] = p;
}

// ---------------------------------------------------------------------------
// Gather SpMM, bf16 X. One 64-lane wave per row, 4 cols/lane, 2-edge unroll.
// FUSE: in-place h = relu(acc + h) written bf16. Else: write fp32 out.
// ---------------------------------------------------------------------------
template <bool FUSE>
__global__ __launch_bounds__(256) void spmm_bf16(const int* __restrict__ row_ptr,
                                                 const int2* __restrict__ cvp,
                                                 const unsigned short* __restrict__ X,
                                                 unsigned short* __restrict__ Ybf,
                                                 float* __restrict__ Yf) {
    const int wid  = (blockIdx.x * 256 + threadIdx.x) >> 6;
    const int lane = threadIdx.x & 63;
    if (wid >= N_TOTAL) return;
    const int beg = row_ptr[wid], end = row_ptr[wid + 1];

    float a0 = 0.f, a1 = 0.f, a2 = 0.f, a3 = 0.f;
    int e = beg;
    for (; e + 1 < end; e += 2) {
        const int2 p0 = cvp[e], p1 = cvp[e + 1];
        const float v0 = __builtin_bit_cast(float, p0.y);
        const float v1 = __builtin_bit_cast(float, p1.y);
        const ushort4v x0 = *(const ushort4v*)(X + (size_t)p0.x * HID + lane * 4);
        const ushort4v x1 = *(const ushort4v*)(X + (size_t)p1.x * HID + lane * 4);
        a0 = fmaf(v0, bf2f(x0[0]), a0); a1 = fmaf(v0, bf2f(x0[1]), a1);
        a2 = fmaf(v0, bf2f(x0[2]), a2); a3 = fmaf(v0, bf2f(x0[3]), a3);
        a0 = fmaf(v1, bf2f(x1[0]), a0); a1 = fmaf(v1, bf2f(x1[1]), a1);
        a2 = fmaf(v1, bf2f(x1[2]), a2); a3 = fmaf(v1, bf2f(x1[3]), a3);
    }
    if (e < end) {
        const int2 p0 = cvp[e];
        const float v0 = __builtin_bit_cast(float, p0.y);
        const ushort4v x0 = *(const ushort4v*)(X + (size_t)p0.x * HID + lane * 4);
        a0 = fmaf(v0, bf2f(x0[0]), a0); a1 = fmaf(v0, bf2f(x0[1]), a1);
        a2 = fmaf(v0, bf2f(x0[2]), a2); a3 = fmaf(v0, bf2f(x0[3]), a3);
    }

    if (FUSE) {
        unsigned short* yp = Ybf + (size_t)wid * HID + lane * 4;
        const ushort4v rv = *(const ushort4v*)yp;
        a0 = fmaxf(a0 + bf2f(rv[0]), 0.f);
        a1 = fmaxf(a1 + bf2f(rv[1]), 0.f);
        a2 = fmaxf(a2 + bf2f(rv[2]), 0.f);
        a3 = fmaxf(a3 + bf2f(rv[3]), 0.f);
        ushort4v o; o[0] = f2bf(a0); o[1] = f2bf(a1); o[2] = f2bf(a2); o[3] = f2bf(a3);
        *(ushort4v*)yp = o;
    } else {
        f32x4 o = {a0, a1, a2, a3};
        *(f32x4*)(Yf + (size_t)wid * HID + lane * 4) = o;
    }
}

extern "C" void kernel_launch(void* const* d_in, const int* in_sizes, int n_in,
                              void* d_out, int out_size, void* d_ws, size_t ws_size,
                              hipStream_t stream) {
    const float* user_feat = (const float*)d_in[0];
    const float* item_feat = (const float*)d_in[1];
    const int*   edge_rows = (const int*)d_in[2];
    const int*   edge_cols = (const int*)d_in[3];
    const float* edge_vals = (const float*)d_in[4];
    const float* W0    = (const float*)d_in[5];
    const float* b0    = (const float*)d_in[6];
    const float* Wres0 = (const float*)d_in[7];
    const float* W1    = (const float*)d_in[8];
    const float* b1    = (const float*)d_in[9];
    float* out = (float*)d_out;

    char* ws = (char*)d_ws;
    auto take = [&](size_t bytes) { char* p = ws; ws += (bytes + 255) & ~(size_t)255; return p; };
    unsigned short* x      = (unsigned short*)take((size_t)M_PAD * HID * 2);
    unsigned short* h      = (unsigned short*)take((size_t)M_PAD * HID * 2);
    unsigned short* feats  = (unsigned short*)take((size_t)M_PAD * IN_DIM * 2);
    unsigned short* Wcat_t = (unsigned short*)take(512 * IN_DIM * 2);
    unsigned short* W1_t   = (unsigned short*)take(HID * HID * 2);
    int*   row_ptr = (int*)take((N_TOTAL + 1) * 4);
    int*   cnt     = (int*)take(N_TOTAL * 4);
    int*   nxt     = (int*)take(N_TOTAL * 4);
    int*   bsums   = (int*)take(128 * 4);
    int2*  cvp     = (int2*)take((size_t)NEDGES * 8);

    const dim3 blk(256);
    const int nscan = (N_TOTAL + SCAN_B - 1) / SCAN_B;

    // ---- Prep (bf16 casts) ----
    prep_feats<<<(N_TOTAL * IN_DIM / 8 + 255) / 256, blk, 0, stream>>>(user_feat, item_feat, feats);
    prep_weights<<<(512 * IN_DIM + HID * HID) / 256, blk, 0, stream>>>(W0, Wres0, W1, Wcat_t, W1_t);

    // ---- CSR build ----
    hipMemsetAsync(cnt, 0, N_TOTAL * 4, stream);
    edge_histogram<<<(NEDGES + 255) / 256, blk, 0, stream>>>(edge_rows, cnt);
    scan_blocks<<<nscan, SCAN_B, 0, stream>>>(cnt, row_ptr, bsums);
    scan_sums<<<1, 128, 0, stream>>>(bsums, nscan);
    scan_apply<<<nscan, SCAN_B, 0, stream>>>(row_ptr, bsums, nxt);
    csr_fill<<<(NEDGES + 255) / 256, blk, 0, stream>>>(edge_rows, edge_cols, edge_vals,
                                                       nxt, cvp);

    // ---- Layer 0: x = A@W0+b0 (colgrp 0), h = A@Wres0 (colgrp 1) ----
    mfma_gemm2<IN_DIM, 1><<<dim3(M_PAD / 64, 2), blk, 0, stream>>>(feats, Wcat_t, b0, x, h);

    // ---- h = relu(spmm(x) + h) in place ----
    const int spmm_blocks = (N_TOTAL * 64 + 255) / 256;
    spmm_bf16<true><<<spmm_blocks, blk, 0, stream>>>(row_ptr, cvp, x, h, nullptr);

    // ---- Layer 1: x2 = h@W1 + b1 ----
    mfma_gemm2<HID, 0><<<dim3(M_PAD / 64, 1), blk, 0, stream>>>(h, W1_t, b1, x, nullptr);

    // ---- out = spmm(x2), fp32 ----
    spmm_bf16<false><<<spmm_blocks, blk, 0, stream>>>(row_ptr, cvp, x, nullptr, out);
}